// Round 1
// baseline (404.347 us; speedup 1.0000x reference)
//
#include <hip/hip_runtime.h>

#define N_NODES 65536
#define N_EDGES 1048576
#define D 64

// ---------------------------------------------------------------------------
// Detect whether edge_index was delivered as int64 (JAX x64 enabled) or int32
// (default). int64 values < 2^17 => hi 32-bit word of every element is 0.
// For int32 data the odd-position words are random indices in [0, 65536);
// 64 consecutive zeros has probability ~(1/65537)^64 ~= 0.
// ---------------------------------------------------------------------------
__global__ void detect_kernel(const unsigned* ei, int* flag) {
    if (threadIdx.x == 0 && blockIdx.x == 0) {
        int is64 = 1;
        for (int i = 0; i < 64; ++i) {
            if (ei[2 * i + 1] != 0u) { is64 = 0; break; }
        }
        *flag = is64;
    }
}

__device__ __forceinline__ int edge_at(const void* ei, int is64, long long pos) {
    if (is64) return (int)((const long long*)ei)[pos];
    return ((const int*)ei)[pos];
}

// In-degree over dst.
__global__ void degree_kernel(const void* ei, const int* flag, unsigned* deg) {
    const int is64 = *flag;
    int tid = blockIdx.x * blockDim.x + threadIdx.x;
    int stride = gridDim.x * blockDim.x;
    for (int e = tid; e < N_EDGES; e += stride) {
        int dst = edge_at(ei, is64, (long long)N_EDGES + e);
        atomicAdd(&deg[dst], 1u);
    }
}

__global__ void invsqrt_kernel(const unsigned* deg, float* inv) {
    int n = blockIdx.x * blockDim.x + threadIdx.x;
    if (n < N_NODES) {
        unsigned d = deg[n];
        inv[n] = (d > 0u) ? rsqrtf((float)d) : 0.0f;
    }
}

// One wave per edge: lane d handles feature d. Coalesced 256B gather of
// x[src] row, coalesced 256B atomic scatter into h[dst] row.
__global__ __launch_bounds__(256) void scatter_kernel(const void* ei, const int* flag,
                                                      const float* __restrict__ x,
                                                      const float* __restrict__ inv,
                                                      float* __restrict__ h) {
    const int is64 = *flag;
    const int lane = threadIdx.x & 63;
    int wid = (blockIdx.x * blockDim.x + threadIdx.x) >> 6;
    int nw = (gridDim.x * blockDim.x) >> 6;
    for (int e = wid; e < N_EDGES; e += nw) {
        int src = edge_at(ei, is64, e);
        int dst = edge_at(ei, is64, (long long)N_EDGES + e);
        float w = inv[src] * inv[dst];
        float val = x[src * D + lane] * w;
        atomicAdd(&h[dst * D + lane], val);
    }
}

// out = leaky(h@W1 + b1) + leaky((x*h)@W2 + b2), in place over h (= d_out).
// One wave per row; lane j computes output feature j. W1/W2 staged in LDS
// [k][j] so lane j reads stride-1 (2 lanes/bank on 32 banks -> conflict-free).
__global__ __launch_bounds__(256) void dense_kernel(const float* __restrict__ x,
                                                    const float* __restrict__ h,
                                                    const float* __restrict__ W1,
                                                    const float* __restrict__ b1,
                                                    const float* __restrict__ W2,
                                                    const float* __restrict__ b2,
                                                    float* __restrict__ out) {
    __shared__ float W1s[D * D];
    __shared__ float W2s[D * D];
    for (int i = threadIdx.x; i < D * D; i += blockDim.x) {
        W1s[i] = W1[i];
        W2s[i] = W2[i];
    }
    __syncthreads();

    const int lane = threadIdx.x & 63;
    int wid = blockIdx.x * (blockDim.x >> 6) + (threadIdx.x >> 6);
    int nw = gridDim.x * (blockDim.x >> 6);
    const float bb1 = b1[lane];
    const float bb2 = b2[lane];

    for (int row = wid; row < N_NODES; row += nw) {
        float hv = h[row * D + lane];
        float xv = x[row * D + lane];
        float gv = xv * hv;
        float a1 = bb1, a2 = bb2;
#pragma unroll
        for (int k = 0; k < D; ++k) {
            a1 = fmaf(__shfl(hv, k), W1s[k * D + lane], a1);
            a2 = fmaf(__shfl(gv, k), W2s[k * D + lane], a2);
        }
        a1 = (a1 >= 0.f) ? a1 : 0.2f * a1;
        a2 = (a2 >= 0.f) ? a2 : 0.2f * a2;
        out[row * D + lane] = a1 + a2;  // same address as h read above: safe
    }
}

extern "C" void kernel_launch(void* const* d_in, const int* in_sizes, int n_in,
                              void* d_out, int out_size, void* d_ws, size_t ws_size,
                              hipStream_t stream) {
    const float* x  = (const float*)d_in[0];
    const void*  ei = d_in[1];
    const float* W1 = (const float*)d_in[2];
    const float* b1 = (const float*)d_in[3];
    const float* W2 = (const float*)d_in[4];
    const float* b2 = (const float*)d_in[5];
    float* out = (float*)d_out;

    char* ws = (char*)d_ws;
    int* flag       = (int*)ws;                              // 256 B slot
    unsigned* deg   = (unsigned*)(ws + 256);                 // 256 KB
    float* inv      = (float*)(ws + 256 + N_NODES * 4);      // 256 KB

    // h accumulates directly in d_out; must be zeroed every call.
    hipMemsetAsync(d_out, 0, (size_t)out_size * sizeof(float), stream);
    hipMemsetAsync(deg, 0, N_NODES * sizeof(unsigned), stream);

    detect_kernel<<<1, 64, 0, stream>>>((const unsigned*)ei, flag);
    degree_kernel<<<2048, 256, 0, stream>>>(ei, flag, deg);
    invsqrt_kernel<<<N_NODES / 256, 256, 0, stream>>>(deg, inv);
    scatter_kernel<<<8192, 256, 0, stream>>>(ei, flag, x, inv, out);
    dense_kernel<<<2048, 256, 0, stream>>>(x, out, W1, b1, W2, b2, out);
}

// Round 2
// 354.048 us; speedup vs baseline: 1.1421x; 1.1421x over previous
//
#include <hip/hip_runtime.h>

#define N_NODES 65536
#define N_EDGES 1048576
#define D 64

// ---------------------------------------------------------------------------
// Detect int64 vs int32 edge_index delivery (see round 0 notes).
// ---------------------------------------------------------------------------
__global__ void detect_kernel(const unsigned* ei, int* flag) {
    if (threadIdx.x == 0 && blockIdx.x == 0) {
        int is64 = 1;
        for (int i = 0; i < 64; ++i) {
            if (ei[2 * i + 1] != 0u) { is64 = 0; break; }
        }
        *flag = is64;
    }
}

__device__ __forceinline__ int edge_at(const void* ei, int is64, long long pos) {
    if (is64) return (int)((const long long*)ei)[pos];
    return ((const int*)ei)[pos];
}

// In-degree over dst (int atomics into 256KB, cheap).
__global__ void degree_kernel(const void* ei, const int* flag, unsigned* deg) {
    const int is64 = *flag;
    int tid = blockIdx.x * blockDim.x + threadIdx.x;
    int stride = gridDim.x * blockDim.x;
    for (int e = tid; e < N_EDGES; e += stride) {
        int dst = edge_at(ei, is64, (long long)N_EDGES + e);
        atomicAdd(&deg[dst], 1u);
    }
}

__global__ void invsqrt_kernel(const unsigned* deg, float* inv) {
    int n = blockIdx.x * blockDim.x + threadIdx.x;
    if (n < N_NODES) {
        unsigned d = deg[n];
        inv[n] = (d > 0u) ? rsqrtf((float)d) : 0.0f;
    }
}

// Exclusive prefix sum of deg[65536] -> row_start[65537], duplicate to cursor.
// Single block, 1024 threads, 64 elements/thread.
__global__ __launch_bounds__(1024) void scan_kernel(const unsigned* __restrict__ deg,
                                                    unsigned* __restrict__ row_start,
                                                    unsigned* __restrict__ cursor) {
    __shared__ unsigned partial[1024];
    const int t = threadIdx.x;
    unsigned sum = 0;
    for (int i = 0; i < 64; ++i) sum += deg[t * 64 + i];
    partial[t] = sum;
    __syncthreads();
    for (int off = 1; off < 1024; off <<= 1) {
        unsigned v = (t >= off) ? partial[t - off] : 0u;
        __syncthreads();
        partial[t] += v;
        __syncthreads();
    }
    unsigned run = (t > 0) ? partial[t - 1] : 0u;
    for (int i = 0; i < 64; ++i) {
        unsigned idx = t * 64 + i;
        row_start[idx] = run;
        cursor[idx] = run;
        run += deg[idx];
    }
    if (t == 1023) row_start[N_NODES] = run;  // == N_EDGES
}

// Counting-sort scatter: place each edge's src into its dst segment.
__global__ void sortscatter_kernel(const void* ei, const int* flag,
                                   unsigned* cursor, int* src_sorted) {
    const int is64 = *flag;
    int tid = blockIdx.x * blockDim.x + threadIdx.x;
    int stride = gridDim.x * blockDim.x;
    for (int e = tid; e < N_EDGES; e += stride) {
        int src = edge_at(ei, is64, e);
        int dst = edge_at(ei, is64, (long long)N_EDGES + e);
        unsigned pos = atomicAdd(&cursor[dst], 1u);
        src_sorted[pos] = src;
    }
}

// Atomic-free segmented SpMM: one wave per dst node, lane = feature.
// h[n] = inv[n] * sum_{e in seg(n)} inv[src_e] * x[src_e, :]
__global__ __launch_bounds__(256) void spmm_kernel(const int* __restrict__ src_sorted,
                                                   const unsigned* __restrict__ row_start,
                                                   const float* __restrict__ x,
                                                   const float* __restrict__ inv,
                                                   float* __restrict__ h) {
    const int lane = threadIdx.x & 63;
    int wid = (blockIdx.x * blockDim.x + threadIdx.x) >> 6;
    int nw = (gridDim.x * blockDim.x) >> 6;
    for (int n = wid; n < N_NODES; n += nw) {
        const unsigned start = row_start[n];
        const unsigned end = row_start[n + 1];
        float acc = 0.f;
        for (unsigned base = start; base < end; base += 64u) {
            const int cnt = (int)min(64u, end - base);
            int s_l = (lane < cnt) ? src_sorted[base + lane] : 0;
            float w_l = (lane < cnt) ? inv[s_l] : 0.f;
            for (int i = 0; i < cnt; ++i) {
                int s = __shfl(s_l, i);
                float wv = __shfl(w_l, i);
                acc = fmaf(wv, x[s * D + lane], acc);
            }
        }
        h[n * D + lane] = acc * inv[n];
    }
}

// out = leaky(h@W1 + b1) + leaky((x*h)@W2 + b2), in place over h (= d_out).
__global__ __launch_bounds__(256) void dense_kernel(const float* __restrict__ x,
                                                    const float* __restrict__ h,
                                                    const float* __restrict__ W1,
                                                    const float* __restrict__ b1,
                                                    const float* __restrict__ W2,
                                                    const float* __restrict__ b2,
                                                    float* __restrict__ out) {
    __shared__ float W1s[D * D];
    __shared__ float W2s[D * D];
    for (int i = threadIdx.x; i < D * D; i += blockDim.x) {
        W1s[i] = W1[i];
        W2s[i] = W2[i];
    }
    __syncthreads();

    const int lane = threadIdx.x & 63;
    int wid = blockIdx.x * (blockDim.x >> 6) + (threadIdx.x >> 6);
    int nw = gridDim.x * (blockDim.x >> 6);
    const float bb1 = b1[lane];
    const float bb2 = b2[lane];

    for (int row = wid; row < N_NODES; row += nw) {
        float hv = h[row * D + lane];
        float xv = x[row * D + lane];
        float gv = xv * hv;
        float a1 = bb1, a2 = bb2;
#pragma unroll
        for (int k = 0; k < D; ++k) {
            a1 = fmaf(__shfl(hv, k), W1s[k * D + lane], a1);
            a2 = fmaf(__shfl(gv, k), W2s[k * D + lane], a2);
        }
        a1 = (a1 >= 0.f) ? a1 : 0.2f * a1;
        a2 = (a2 >= 0.f) ? a2 : 0.2f * a2;
        out[row * D + lane] = a1 + a2;
    }
}

extern "C" void kernel_launch(void* const* d_in, const int* in_sizes, int n_in,
                              void* d_out, int out_size, void* d_ws, size_t ws_size,
                              hipStream_t stream) {
    const float* x  = (const float*)d_in[0];
    const void*  ei = d_in[1];
    const float* W1 = (const float*)d_in[2];
    const float* b1 = (const float*)d_in[3];
    const float* W2 = (const float*)d_in[4];
    const float* b2 = (const float*)d_in[5];
    float* out = (float*)d_out;

    char* ws = (char*)d_ws;
    const size_t K = (size_t)N_NODES * 4;  // 256 KB
    int*      flag       = (int*)ws;                       // 256 B
    unsigned* deg        = (unsigned*)(ws + 256);          // K
    float*    inv        = (float*)(ws + 256 + K);         // K
    unsigned* row_start  = (unsigned*)(ws + 256 + 2 * K);  // K + 256 (65537 entries)
    unsigned* cursor     = (unsigned*)(ws + 512 + 3 * K);  // K
    int*      src_sorted = (int*)(ws + 512 + 4 * K);       // 4 MB

    hipMemsetAsync(deg, 0, K, stream);

    detect_kernel<<<1, 64, 0, stream>>>((const unsigned*)ei, flag);
    degree_kernel<<<1024, 256, 0, stream>>>(ei, flag, deg);
    scan_kernel<<<1, 1024, 0, stream>>>(deg, row_start, cursor);
    invsqrt_kernel<<<N_NODES / 256, 256, 0, stream>>>(deg, inv);
    sortscatter_kernel<<<1024, 256, 0, stream>>>(ei, flag, cursor, src_sorted);
    spmm_kernel<<<16384, 256, 0, stream>>>(src_sorted, row_start, x, inv, out);
    dense_kernel<<<2048, 256, 0, stream>>>(x, out, W1, b1, W2, b2, out);
}

// Round 3
// 203.649 us; speedup vs baseline: 1.9855x; 1.7385x over previous
//
#include <hip/hip_runtime.h>

#define N_NODES 65536
#define N_EDGES 1048576
#define D 64

typedef __bf16 bf16x8 __attribute__((ext_vector_type(8)));
typedef float f32x4 __attribute__((ext_vector_type(4)));

// ---------------------------------------------------------------------------
// Detect int64 vs int32 edge_index delivery (see round 0 notes).
// ---------------------------------------------------------------------------
__global__ void detect_kernel(const unsigned* ei, int* flag) {
    if (threadIdx.x == 0 && blockIdx.x == 0) {
        int is64 = 1;
        for (int i = 0; i < 64; ++i) {
            if (ei[2 * i + 1] != 0u) { is64 = 0; break; }
        }
        *flag = is64;
    }
}

__device__ __forceinline__ int edge_at(const void* ei, int is64, long long pos) {
    if (is64) return (int)((const long long*)ei)[pos];
    return ((const int*)ei)[pos];
}

__global__ void degree_kernel(const void* ei, const int* flag, unsigned* deg) {
    const int is64 = *flag;
    int tid = blockIdx.x * blockDim.x + threadIdx.x;
    int stride = gridDim.x * blockDim.x;
    for (int e = tid; e < N_EDGES; e += stride) {
        int dst = edge_at(ei, is64, (long long)N_EDGES + e);
        atomicAdd(&deg[dst], 1u);
    }
}

__global__ void invsqrt_kernel(const unsigned* deg, float* inv) {
    int n = blockIdx.x * blockDim.x + threadIdx.x;
    if (n < N_NODES) {
        unsigned d = deg[n];
        inv[n] = (d > 0u) ? rsqrtf((float)d) : 0.0f;
    }
}

// --------------------- 3-phase exclusive scan of deg -----------------------
__global__ __launch_bounds__(256) void scanA_kernel(const unsigned* __restrict__ deg,
                                                    unsigned* __restrict__ bsum) {
    __shared__ unsigned s[256];
    const int t = threadIdx.x;
    s[t] = deg[blockIdx.x * 256 + t];
    __syncthreads();
    for (int off = 128; off; off >>= 1) {
        if (t < off) s[t] += s[t + off];
        __syncthreads();
    }
    if (t == 0) bsum[blockIdx.x] = s[0];
}

__global__ __launch_bounds__(256) void scanB_kernel(const unsigned* __restrict__ bsum,
                                                    unsigned* __restrict__ boff) {
    __shared__ unsigned s[256];
    const int t = threadIdx.x;
    unsigned own = bsum[t];
    s[t] = own;
    __syncthreads();
    for (int off = 1; off < 256; off <<= 1) {
        unsigned v = (t >= off) ? s[t - off] : 0u;
        __syncthreads();
        s[t] += v;
        __syncthreads();
    }
    boff[t] = s[t] - own;  // exclusive
}

__global__ __launch_bounds__(256) void scanC_kernel(const unsigned* __restrict__ deg,
                                                    const unsigned* __restrict__ boff,
                                                    unsigned* __restrict__ row_start,
                                                    unsigned* __restrict__ cursor) {
    __shared__ unsigned s[256];
    const int t = threadIdx.x;
    const int g = blockIdx.x * 256 + t;
    unsigned own = deg[g];
    s[t] = own;
    __syncthreads();
    for (int off = 1; off < 256; off <<= 1) {
        unsigned v = (t >= off) ? s[t - off] : 0u;
        __syncthreads();
        s[t] += v;
        __syncthreads();
    }
    unsigned excl = s[t] - own + boff[blockIdx.x];
    row_start[g] = excl;
    cursor[g] = excl;
    if (g == 0) row_start[N_NODES] = N_EDGES;
}

// Counting-sort scatter: place each edge's src into its dst segment.
__global__ void sortscatter_kernel(const void* ei, const int* flag,
                                   unsigned* cursor, int* src_sorted) {
    const int is64 = *flag;
    int tid = blockIdx.x * blockDim.x + threadIdx.x;
    int stride = gridDim.x * blockDim.x;
    for (int e = tid; e < N_EDGES; e += stride) {
        int src = edge_at(ei, is64, e);
        int dst = edge_at(ei, is64, (long long)N_EDGES + e);
        unsigned pos = atomicAdd(&cursor[dst], 1u);
        src_sorted[pos] = src;
    }
}

// Atomic-free segmented SpMM, unroll-4 with independent accumulators so four
// gathers are in flight per wave. h[n] = inv[n] * sum inv[s]*x[s,:]
__global__ __launch_bounds__(256) void spmm_kernel(const int* __restrict__ src_sorted,
                                                   const unsigned* __restrict__ row_start,
                                                   const float* __restrict__ x,
                                                   const float* __restrict__ inv,
                                                   float* __restrict__ h) {
    const int lane = threadIdx.x & 63;
    int wid = (blockIdx.x * blockDim.x + threadIdx.x) >> 6;
    int nw = (gridDim.x * blockDim.x) >> 6;
    for (int n = wid; n < N_NODES; n += nw) {
        const unsigned start = row_start[n];
        const unsigned end = row_start[n + 1];
        float a0 = 0.f, a1 = 0.f, a2 = 0.f, a3 = 0.f;
        unsigned i = start;
        for (; i + 4 <= end; i += 4) {
            int s0 = src_sorted[i];
            int s1 = src_sorted[i + 1];
            int s2 = src_sorted[i + 2];
            int s3 = src_sorted[i + 3];
            float w0 = inv[s0], w1 = inv[s1], w2 = inv[s2], w3 = inv[s3];
            a0 = fmaf(w0, x[s0 * D + lane], a0);
            a1 = fmaf(w1, x[s1 * D + lane], a1);
            a2 = fmaf(w2, x[s2 * D + lane], a2);
            a3 = fmaf(w3, x[s3 * D + lane], a3);
        }
        for (; i < end; ++i) {
            int s = src_sorted[i];
            a0 = fmaf(inv[s], x[s * D + lane], a0);
        }
        h[n * D + lane] = (a0 + a1 + a2 + a3) * inv[n];
    }
}

// out = leaky(h@W1+b1) + leaky((x*h)@W2+b2) via mfma_f32_16x16x32_bf16.
// One wave per 16-row block. W-frags live in registers for the whole kernel.
// hout aliases h (read-before-write within the owning wave only).
__global__ __launch_bounds__(256) void dense_mfma_kernel(const float* __restrict__ x,
                                                         const float* __restrict__ W1,
                                                         const float* __restrict__ b1,
                                                         const float* __restrict__ W2,
                                                         const float* __restrict__ b2,
                                                         float* hout) {
    const int lane = threadIdx.x & 63;
    const int lo = lane & 15;   // A-row / B-col / D-col
    const int hi = lane >> 4;   // k-chunk selector / D-row group

    // Preload B-frags: B[k][n] with k = kt*32 + hi*8 + j, n = nt*16 + lo
    bf16x8 bw1[2][4], bw2[2][4];
#pragma unroll
    for (int kt = 0; kt < 2; ++kt)
#pragma unroll
        for (int nt = 0; nt < 4; ++nt) {
            bf16x8 v1, v2;
#pragma unroll
            for (int j = 0; j < 8; ++j) {
                int k = kt * 32 + hi * 8 + j;
                int n = nt * 16 + lo;
                v1[j] = (__bf16)W1[k * D + n];
                v2[j] = (__bf16)W2[k * D + n];
            }
            bw1[kt][nt] = v1;
            bw2[kt][nt] = v2;
        }
    float bb1[4], bb2[4];
#pragma unroll
    for (int nt = 0; nt < 4; ++nt) {
        bb1[nt] = b1[nt * 16 + lo];
        bb2[nt] = b2[nt * 16 + lo];
    }

    int wid = (blockIdx.x * blockDim.x + threadIdx.x) >> 6;
    int nw = (gridDim.x * blockDim.x) >> 6;
    for (int blk = wid; blk < N_NODES / 16; blk += nw) {
        const int rb = blk * 16;
        const float* hrow = hout + (rb + lo) * D;
        const float* xrow = x + (rb + lo) * D;
        bf16x8 ah[2], ag[2];
#pragma unroll
        for (int kt = 0; kt < 2; ++kt) {
            const int c = kt * 32 + hi * 8;
            float4 hv0 = *(const float4*)(hrow + c);
            float4 hv1 = *(const float4*)(hrow + c + 4);
            float4 xv0 = *(const float4*)(xrow + c);
            float4 xv1 = *(const float4*)(xrow + c + 4);
            bf16x8 a, g;
            a[0] = (__bf16)hv0.x; g[0] = (__bf16)(hv0.x * xv0.x);
            a[1] = (__bf16)hv0.y; g[1] = (__bf16)(hv0.y * xv0.y);
            a[2] = (__bf16)hv0.z; g[2] = (__bf16)(hv0.z * xv0.z);
            a[3] = (__bf16)hv0.w; g[3] = (__bf16)(hv0.w * xv0.w);
            a[4] = (__bf16)hv1.x; g[4] = (__bf16)(hv1.x * xv1.x);
            a[5] = (__bf16)hv1.y; g[5] = (__bf16)(hv1.y * xv1.y);
            a[6] = (__bf16)hv1.z; g[6] = (__bf16)(hv1.z * xv1.z);
            a[7] = (__bf16)hv1.w; g[7] = (__bf16)(hv1.w * xv1.w);
            ah[kt] = a;
            ag[kt] = g;
        }
        f32x4 acc1[4], acc2[4];
#pragma unroll
        for (int nt = 0; nt < 4; ++nt) {
            acc1[nt] = (f32x4){0.f, 0.f, 0.f, 0.f};
            acc2[nt] = (f32x4){0.f, 0.f, 0.f, 0.f};
        }
#pragma unroll
        for (int kt = 0; kt < 2; ++kt)
#pragma unroll
            for (int nt = 0; nt < 4; ++nt) {
                acc1[nt] = __builtin_amdgcn_mfma_f32_16x16x32_bf16(ah[kt], bw1[kt][nt], acc1[nt], 0, 0, 0);
                acc2[nt] = __builtin_amdgcn_mfma_f32_16x16x32_bf16(ag[kt], bw2[kt][nt], acc2[nt], 0, 0, 0);
            }
#pragma unroll
        for (int nt = 0; nt < 4; ++nt)
#pragma unroll
            for (int r = 0; r < 4; ++r) {
                float a1 = acc1[nt][r] + bb1[nt];
                float a2 = acc2[nt][r] + bb2[nt];
                a1 = (a1 >= 0.f) ? a1 : 0.2f * a1;
                a2 = (a2 >= 0.f) ? a2 : 0.2f * a2;
                hout[(rb + hi * 4 + r) * D + nt * 16 + lo] = a1 + a2;
            }
    }
}

extern "C" void kernel_launch(void* const* d_in, const int* in_sizes, int n_in,
                              void* d_out, int out_size, void* d_ws, size_t ws_size,
                              hipStream_t stream) {
    const float* x  = (const float*)d_in[0];
    const void*  ei = d_in[1];
    const float* W1 = (const float*)d_in[2];
    const float* b1 = (const float*)d_in[3];
    const float* W2 = (const float*)d_in[4];
    const float* b2 = (const float*)d_in[5];
    float* out = (float*)d_out;

    char* ws = (char*)d_ws;
    const size_t K = (size_t)N_NODES * 4;  // 256 KB
    int*      flag       = (int*)ws;                          // 256 B
    unsigned* deg        = (unsigned*)(ws + 256);             // K
    float*    inv        = (float*)(ws + 256 + K);            // K
    unsigned* row_start  = (unsigned*)(ws + 256 + 2 * K);     // K + 256 (65537)
    unsigned* cursor     = (unsigned*)(ws + 512 + 3 * K);     // K
    unsigned* bsum       = (unsigned*)(ws + 512 + 4 * K);     // 1 KB
    unsigned* boff       = (unsigned*)(ws + 512 + 4 * K + 1024);  // 1 KB
    int*      src_sorted = (int*)(ws + 512 + 4 * K + 2048);   // 4 MB

    hipMemsetAsync(deg, 0, K, stream);

    detect_kernel<<<1, 64, 0, stream>>>((const unsigned*)ei, flag);
    degree_kernel<<<2048, 256, 0, stream>>>(ei, flag, deg);
    invsqrt_kernel<<<N_NODES / 256, 256, 0, stream>>>(deg, inv);
    scanA_kernel<<<256, 256, 0, stream>>>(deg, bsum);
    scanB_kernel<<<1, 256, 0, stream>>>(bsum, boff);
    scanC_kernel<<<256, 256, 0, stream>>>(deg, boff, row_start, cursor);
    sortscatter_kernel<<<2048, 256, 0, stream>>>(ei, flag, cursor, src_sorted);
    spmm_kernel<<<4096, 256, 0, stream>>>(src_sorted, row_start, x, inv, out);
    dense_mfma_kernel<<<512, 256, 0, stream>>>(x, W1, b1, W2, b2, out);
}

// Round 4
// 123.753 us; speedup vs baseline: 3.2674x; 1.6456x over previous
//
#include <hip/hip_runtime.h>

#define N_NODES 65536
#define N_EDGES 1048576
#define D 64
#define NB 256                  // major buckets = dst >> 8
#define CHUNK (N_EDGES / NB)    // 4096 edges per histA/scatterA workgroup

typedef __bf16 bf16x8 __attribute__((ext_vector_type(8)));
typedef float f32x4 __attribute__((ext_vector_type(4)));

// ---------------------------------------------------------------------------
// Detect int64 vs int32 edge_index delivery (see round 0 notes).
// ---------------------------------------------------------------------------
__global__ void detect_kernel(const unsigned* ei, int* flag) {
    if (threadIdx.x == 0 && blockIdx.x == 0) {
        int is64 = 1;
        for (int i = 0; i < 64; ++i) {
            if (ei[2 * i + 1] != 0u) { is64 = 0; break; }
        }
        *flag = is64;
    }
}

__device__ __forceinline__ int edge_at(const void* ei, int is64, long long pos) {
    if (is64) return (int)((const long long*)ei)[pos];
    return ((const int*)ei)[pos];
}

// Pass A1: per-chunk histogram over dst>>8. H layout: H[bucket*NB + wg]
// (transposed so scanH reads contiguously per bucket).
__global__ __launch_bounds__(256) void histA_kernel(const void* ei, const int* flag,
                                                    unsigned* __restrict__ H) {
    __shared__ unsigned hist[NB];
    const int is64 = *flag;
    const int t = threadIdx.x;
    const int w = blockIdx.x;
    hist[t] = 0;
    __syncthreads();
    const int base = w * CHUNK;
    for (int i = t; i < CHUNK; i += 256) {
        int dst = edge_at(ei, is64, (long long)N_EDGES + base + i);
        atomicAdd(&hist[dst >> 8], 1u);
    }
    __syncthreads();
    H[t * NB + w] = hist[t];
}

// Pass A2: one WG. Thread b: serial exclusive prefix over H[b][*] -> P[b][*],
// then block-scan of bucket totals -> bucket_start[257].
__global__ __launch_bounds__(256) void scanH_kernel(const unsigned* __restrict__ H,
                                                    unsigned* __restrict__ P,
                                                    unsigned* __restrict__ bucket_start) {
    __shared__ unsigned cs[NB];
    const int b = threadIdx.x;
    unsigned run = 0;
#pragma unroll 8
    for (int w = 0; w < NB; ++w) {
        P[b * NB + w] = run;
        run += H[b * NB + w];
    }
    unsigned own = run;
    cs[b] = run;
    __syncthreads();
    for (int off = 1; off < NB; off <<= 1) {
        unsigned v = (b >= off) ? cs[b - off] : 0u;
        __syncthreads();
        cs[b] += v;
        __syncthreads();
    }
    bucket_start[b] = cs[b] - own;
    if (b == NB - 1) bucket_start[NB] = cs[b];
}

// Pass A3: scatter edges into bucket-major order as packed u32:
// src in bits [0,16), dst&255 in bits [16,24). LDS cursors only.
__global__ __launch_bounds__(256) void scatterA_kernel(const void* ei, const int* flag,
                                                       const unsigned* __restrict__ P,
                                                       const unsigned* __restrict__ bucket_start,
                                                       unsigned* __restrict__ pairs) {
    __shared__ unsigned cur[NB];
    const int is64 = *flag;
    const int t = threadIdx.x;
    const int w = blockIdx.x;
    cur[t] = bucket_start[t] + P[t * NB + w];
    __syncthreads();
    const int base = w * CHUNK;
    for (int i = t; i < CHUNK; i += 256) {
        int src = edge_at(ei, is64, base + i);
        int dst = edge_at(ei, is64, (long long)N_EDGES + base + i);
        unsigned pos = atomicAdd(&cur[dst >> 8], 1u);
        pairs[pos] = (unsigned)src | ((unsigned)(dst & 255) << 16);
    }
}

// Pass B: per major bucket: LDS histogram over dstlow (== deg for these 256
// nodes, written densely), LDS scan -> row_start, LDS-cursor scatter -> final
// src_sorted. Zero global atomics.
__global__ __launch_bounds__(256) void bucketB_kernel(const unsigned* __restrict__ pairs,
                                                      const unsigned* __restrict__ bucket_start,
                                                      unsigned* __restrict__ deg,
                                                      unsigned* __restrict__ row_start,
                                                      int* __restrict__ src_sorted) {
    __shared__ unsigned hist[NB];
    __shared__ unsigned sc[NB];
    const int t = threadIdx.x;
    const int b = blockIdx.x;
    const unsigned base = bucket_start[b];
    const unsigned cnt = bucket_start[b + 1] - base;
    hist[t] = 0;
    __syncthreads();
    for (unsigned i = t; i < cnt; i += 256u) {
        atomicAdd(&hist[(pairs[base + i] >> 16) & 255u], 1u);
    }
    __syncthreads();
    const unsigned own = hist[t];
    deg[b * NB + t] = own;
    sc[t] = own;
    __syncthreads();
    for (int off = 1; off < NB; off <<= 1) {
        unsigned v = (t >= off) ? sc[t - off] : 0u;
        __syncthreads();
        sc[t] += v;
        __syncthreads();
    }
    const unsigned excl = sc[t] - own;
    row_start[b * NB + t] = base + excl;
    if (b == NB - 1 && t == 0) row_start[N_NODES] = N_EDGES;
    hist[t] = excl;  // reuse as cursor
    __syncthreads();
    for (unsigned i = t; i < cnt; i += 256u) {
        unsigned p = pairs[base + i];
        unsigned pos = atomicAdd(&hist[(p >> 16) & 255u], 1u);
        src_sorted[base + pos] = (int)(p & 0xFFFFu);
    }
}

__global__ void invsqrt_kernel(const unsigned* deg, float* inv) {
    int n = blockIdx.x * blockDim.x + threadIdx.x;
    if (n < N_NODES) {
        unsigned d = deg[n];
        inv[n] = (d > 0u) ? rsqrtf((float)d) : 0.0f;
    }
}

// Atomic-free segmented SpMM, unroll-4 with independent accumulators.
__global__ __launch_bounds__(256) void spmm_kernel(const int* __restrict__ src_sorted,
                                                   const unsigned* __restrict__ row_start,
                                                   const float* __restrict__ x,
                                                   const float* __restrict__ inv,
                                                   float* __restrict__ h) {
    const int lane = threadIdx.x & 63;
    int wid = (blockIdx.x * blockDim.x + threadIdx.x) >> 6;
    int nw = (gridDim.x * blockDim.x) >> 6;
    for (int n = wid; n < N_NODES; n += nw) {
        const unsigned start = row_start[n];
        const unsigned end = row_start[n + 1];
        float a0 = 0.f, a1 = 0.f, a2 = 0.f, a3 = 0.f;
        unsigned i = start;
        for (; i + 4 <= end; i += 4) {
            int s0 = src_sorted[i];
            int s1 = src_sorted[i + 1];
            int s2 = src_sorted[i + 2];
            int s3 = src_sorted[i + 3];
            float w0 = inv[s0], w1 = inv[s1], w2 = inv[s2], w3 = inv[s3];
            a0 = fmaf(w0, x[s0 * D + lane], a0);
            a1 = fmaf(w1, x[s1 * D + lane], a1);
            a2 = fmaf(w2, x[s2 * D + lane], a2);
            a3 = fmaf(w3, x[s3 * D + lane], a3);
        }
        for (; i < end; ++i) {
            int s = src_sorted[i];
            a0 = fmaf(inv[s], x[s * D + lane], a0);
        }
        h[n * D + lane] = (a0 + a1 + a2 + a3) * inv[n];
    }
}

// out = leaky(h@W1+b1) + leaky((x*h)@W2+b2) via mfma_f32_16x16x32_bf16.
__global__ __launch_bounds__(256) void dense_mfma_kernel(const float* __restrict__ x,
                                                         const float* __restrict__ W1,
                                                         const float* __restrict__ b1,
                                                         const float* __restrict__ W2,
                                                         const float* __restrict__ b2,
                                                         float* hout) {
    const int lane = threadIdx.x & 63;
    const int lo = lane & 15;
    const int hi = lane >> 4;

    bf16x8 bw1[2][4], bw2[2][4];
#pragma unroll
    for (int kt = 0; kt < 2; ++kt)
#pragma unroll
        for (int nt = 0; nt < 4; ++nt) {
            bf16x8 v1, v2;
#pragma unroll
            for (int j = 0; j < 8; ++j) {
                int k = kt * 32 + hi * 8 + j;
                int n = nt * 16 + lo;
                v1[j] = (__bf16)W1[k * D + n];
                v2[j] = (__bf16)W2[k * D + n];
            }
            bw1[kt][nt] = v1;
            bw2[kt][nt] = v2;
        }
    float bb1[4], bb2[4];
#pragma unroll
    for (int nt = 0; nt < 4; ++nt) {
        bb1[nt] = b1[nt * 16 + lo];
        bb2[nt] = b2[nt * 16 + lo];
    }

    int wid = (blockIdx.x * blockDim.x + threadIdx.x) >> 6;
    int nw = (gridDim.x * blockDim.x) >> 6;
    for (int blk = wid; blk < N_NODES / 16; blk += nw) {
        const int rb = blk * 16;
        const float* hrow = hout + (rb + lo) * D;
        const float* xrow = x + (rb + lo) * D;
        bf16x8 ah[2], ag[2];
#pragma unroll
        for (int kt = 0; kt < 2; ++kt) {
            const int c = kt * 32 + hi * 8;
            float4 hv0 = *(const float4*)(hrow + c);
            float4 hv1 = *(const float4*)(hrow + c + 4);
            float4 xv0 = *(const float4*)(xrow + c);
            float4 xv1 = *(const float4*)(xrow + c + 4);
            bf16x8 a, g;
            a[0] = (__bf16)hv0.x; g[0] = (__bf16)(hv0.x * xv0.x);
            a[1] = (__bf16)hv0.y; g[1] = (__bf16)(hv0.y * xv0.y);
            a[2] = (__bf16)hv0.z; g[2] = (__bf16)(hv0.z * xv0.z);
            a[3] = (__bf16)hv0.w; g[3] = (__bf16)(hv0.w * xv0.w);
            a[4] = (__bf16)hv1.x; g[4] = (__bf16)(hv1.x * xv1.x);
            a[5] = (__bf16)hv1.y; g[5] = (__bf16)(hv1.y * xv1.y);
            a[6] = (__bf16)hv1.z; g[6] = (__bf16)(hv1.z * xv1.z);
            a[7] = (__bf16)hv1.w; g[7] = (__bf16)(hv1.w * xv1.w);
            ah[kt] = a;
            ag[kt] = g;
        }
        f32x4 acc1[4], acc2[4];
#pragma unroll
        for (int nt = 0; nt < 4; ++nt) {
            acc1[nt] = (f32x4){0.f, 0.f, 0.f, 0.f};
            acc2[nt] = (f32x4){0.f, 0.f, 0.f, 0.f};
        }
#pragma unroll
        for (int kt = 0; kt < 2; ++kt)
#pragma unroll
            for (int nt = 0; nt < 4; ++nt) {
                acc1[nt] = __builtin_amdgcn_mfma_f32_16x16x32_bf16(ah[kt], bw1[kt][nt], acc1[nt], 0, 0, 0);
                acc2[nt] = __builtin_amdgcn_mfma_f32_16x16x32_bf16(ag[kt], bw2[kt][nt], acc2[nt], 0, 0, 0);
            }
#pragma unroll
        for (int nt = 0; nt < 4; ++nt)
#pragma unroll
            for (int r = 0; r < 4; ++r) {
                float a1 = acc1[nt][r] + bb1[nt];
                float a2 = acc2[nt][r] + bb2[nt];
                a1 = (a1 >= 0.f) ? a1 : 0.2f * a1;
                a2 = (a2 >= 0.f) ? a2 : 0.2f * a2;
                hout[(rb + hi * 4 + r) * D + nt * 16 + lo] = a1 + a2;
            }
    }
}

extern "C" void kernel_launch(void* const* d_in, const int* in_sizes, int n_in,
                              void* d_out, int out_size, void* d_ws, size_t ws_size,
                              hipStream_t stream) {
    const float* x  = (const float*)d_in[0];
    const void*  ei = d_in[1];
    const float* W1 = (const float*)d_in[2];
    const float* b1 = (const float*)d_in[3];
    const float* W2 = (const float*)d_in[4];
    const float* b2 = (const float*)d_in[5];
    float* out = (float*)d_out;

    char* ws = (char*)d_ws;
    const size_t K = (size_t)N_NODES * 4;  // 256 KB
    int*      flag         = (int*)ws;                          // 256 B
    unsigned* deg          = (unsigned*)(ws + 256);             // K
    float*    inv          = (float*)(ws + 256 + K);            // K
    unsigned* row_start    = (unsigned*)(ws + 256 + 2 * K);     // K + 256 (65537)
    unsigned* H            = (unsigned*)(ws + 512 + 3 * K);     // K
    unsigned* P            = (unsigned*)(ws + 512 + 4 * K);     // K
    unsigned* bucket_start = (unsigned*)(ws + 512 + 5 * K);     // 1028 B (pad 2 KB)
    int*      src_sorted   = (int*)(ws + 2560 + 5 * K);         // 4 MB

    // pairs scratch lives in d_out: fully written by scatterA before any read,
    // fully overwritten by spmm afterwards -> deterministic.
    unsigned* pairs = (unsigned*)d_out;

    detect_kernel<<<1, 64, 0, stream>>>((const unsigned*)ei, flag);
    histA_kernel<<<NB, 256, 0, stream>>>(ei, flag, H);
    scanH_kernel<<<1, 256, 0, stream>>>(H, P, bucket_start);
    scatterA_kernel<<<NB, 256, 0, stream>>>(ei, flag, P, bucket_start, pairs);
    bucketB_kernel<<<NB, 256, 0, stream>>>(pairs, bucket_start, deg, row_start, src_sorted);
    invsqrt_kernel<<<N_NODES / 256, 256, 0, stream>>>(deg, inv);
    spmm_kernel<<<4096, 256, 0, stream>>>(src_sorted, row_start, x, inv, out);
    dense_mfma_kernel<<<512, 256, 0, stream>>>(x, W1, b1, W2, b2, out);
}

// Round 5
// 122.271 us; speedup vs baseline: 3.3070x; 1.0121x over previous
//
#include <hip/hip_runtime.h>

#define N_NODES 65536
#define N_EDGES 1048576
#define D 64
#define NB 256                  // major buckets = dst >> 8
#define CHUNK (N_EDGES / NB)    // 4096 edges per histA/scatterA workgroup

typedef __bf16 bf16x8 __attribute__((ext_vector_type(8)));
typedef float f32x4 __attribute__((ext_vector_type(4)));

// ---------------------------------------------------------------------------
// Detect int64 vs int32 edge_index delivery (see round 0 notes).
// ---------------------------------------------------------------------------
__global__ void detect_kernel(const unsigned* ei, int* flag) {
    if (threadIdx.x == 0 && blockIdx.x == 0) {
        int is64 = 1;
        for (int i = 0; i < 64; ++i) {
            if (ei[2 * i + 1] != 0u) { is64 = 0; break; }
        }
        *flag = is64;
    }
}

__device__ __forceinline__ int edge_at(const void* ei, int is64, long long pos) {
    if (is64) return (int)((const long long*)ei)[pos];
    return ((const int*)ei)[pos];
}

// Pass A1: per-chunk histogram over dst>>8. H layout: H[bucket*NB + wg].
__global__ __launch_bounds__(256) void histA_kernel(const void* ei, const int* flag,
                                                    unsigned* __restrict__ H) {
    __shared__ unsigned hist[NB];
    const int is64 = *flag;
    const int t = threadIdx.x;
    const int w = blockIdx.x;
    hist[t] = 0;
    __syncthreads();
    const int base = w * CHUNK;
    for (int i = t; i < CHUNK; i += 256) {
        int dst = edge_at(ei, is64, (long long)N_EDGES + base + i);
        atomicAdd(&hist[dst >> 8], 1u);
    }
    __syncthreads();
    H[t * NB + w] = hist[t];
}

// Pass A2: one WG. Thread b: serial exclusive prefix over H[b][*] -> P[b][*],
// then block-scan of bucket totals -> bucket_start[257].
__global__ __launch_bounds__(256) void scanH_kernel(const unsigned* __restrict__ H,
                                                    unsigned* __restrict__ P,
                                                    unsigned* __restrict__ bucket_start) {
    __shared__ unsigned cs[NB];
    const int b = threadIdx.x;
    unsigned run = 0;
#pragma unroll 8
    for (int w = 0; w < NB; ++w) {
        P[b * NB + w] = run;
        run += H[b * NB + w];
    }
    unsigned own = run;
    cs[b] = run;
    __syncthreads();
    for (int off = 1; off < NB; off <<= 1) {
        unsigned v = (b >= off) ? cs[b - off] : 0u;
        __syncthreads();
        cs[b] += v;
        __syncthreads();
    }
    bucket_start[b] = cs[b] - own;
    if (b == NB - 1) bucket_start[NB] = cs[b];
}

// Pass A3: scatter edges into bucket-major order as packed u32:
// src in bits [0,16), dst&255 in bits [16,24). LDS cursors only.
__global__ __launch_bounds__(256) void scatterA_kernel(const void* ei, const int* flag,
                                                       const unsigned* __restrict__ P,
                                                       const unsigned* __restrict__ bucket_start,
                                                       unsigned* __restrict__ pairs) {
    __shared__ unsigned cur[NB];
    const int is64 = *flag;
    const int t = threadIdx.x;
    const int w = blockIdx.x;
    cur[t] = bucket_start[t] + P[t * NB + w];
    __syncthreads();
    const int base = w * CHUNK;
    for (int i = t; i < CHUNK; i += 256) {
        int src = edge_at(ei, is64, base + i);
        int dst = edge_at(ei, is64, (long long)N_EDGES + base + i);
        unsigned pos = atomicAdd(&cur[dst >> 8], 1u);
        pairs[pos] = (unsigned)src | ((unsigned)(dst & 255) << 16);
    }
}

// Pass B: per major bucket: LDS histogram over dstlow (== deg, written
// densely), LDS scan -> row_start, LDS-cursor scatter -> final src_sorted.
__global__ __launch_bounds__(256) void bucketB_kernel(const unsigned* __restrict__ pairs,
                                                      const unsigned* __restrict__ bucket_start,
                                                      unsigned* __restrict__ deg,
                                                      unsigned* __restrict__ row_start,
                                                      int* __restrict__ src_sorted) {
    __shared__ unsigned hist[NB];
    __shared__ unsigned sc[NB];
    const int t = threadIdx.x;
    const int b = blockIdx.x;
    const unsigned base = bucket_start[b];
    const unsigned cnt = bucket_start[b + 1] - base;
    hist[t] = 0;
    __syncthreads();
    for (unsigned i = t; i < cnt; i += 256u) {
        atomicAdd(&hist[(pairs[base + i] >> 16) & 255u], 1u);
    }
    __syncthreads();
    const unsigned own = hist[t];
    deg[b * NB + t] = own;
    sc[t] = own;
    __syncthreads();
    for (int off = 1; off < NB; off <<= 1) {
        unsigned v = (t >= off) ? sc[t - off] : 0u;
        __syncthreads();
        sc[t] += v;
        __syncthreads();
    }
    const unsigned excl = sc[t] - own;
    row_start[b * NB + t] = base + excl;
    if (b == NB - 1 && t == 0) row_start[N_NODES] = N_EDGES;
    hist[t] = excl;  // reuse as cursor
    __syncthreads();
    for (unsigned i = t; i < cnt; i += 256u) {
        unsigned p = pairs[base + i];
        unsigned pos = atomicAdd(&hist[(p >> 16) & 255u], 1u);
        src_sorted[base + pos] = (int)(p & 0xFFFFu);
    }
}

// y[n][d] = bf16( rsqrt(deg[n]) * x[n][d] ) — prefolded source weight,
// halves spmm gather bytes. One thread per 2 features (u32 store).
__global__ __launch_bounds__(256) void y_kernel(const float* __restrict__ x,
                                                const unsigned* __restrict__ deg,
                                                unsigned* __restrict__ y32) {
    int idx = blockIdx.x * blockDim.x + threadIdx.x;  // 0 .. N_NODES*32
    int n = idx >> 5;
    int c = (idx & 31) * 2;
    unsigned d = deg[n];
    float w = d ? rsqrtf((float)d) : 0.f;
    float2 v = *(const float2*)(x + n * D + c);
    unsigned lo = (unsigned)__builtin_bit_cast(unsigned short, (__bf16)(v.x * w));
    unsigned hi = (unsigned)__builtin_bit_cast(unsigned short, (__bf16)(v.y * w));
    y32[idx] = lo | (hi << 16);
}

// Atomic-free segmented SpMM over prefolded bf16 y.
// Lanes 0-31 accumulate even edges, 32-63 odd edges; lane handles feature
// pair 2*(lane&31). Per instruction: 2 random 128B rows. Combine halves via
// shfl_xor(32); h[n] = rsqrt(deg_n) * sum.
__global__ __launch_bounds__(256) void spmm_kernel(const int* __restrict__ src_sorted,
                                                   const unsigned* __restrict__ row_start,
                                                   const unsigned* __restrict__ y32,
                                                   float* __restrict__ h) {
    const int lane = threadIdx.x & 63;
    const int half = lane >> 5;
    const int l31 = lane & 31;
    int wid = (blockIdx.x * blockDim.x + threadIdx.x) >> 6;
    int nw = (gridDim.x * blockDim.x) >> 6;
    for (int n = wid; n < N_NODES; n += nw) {
        const unsigned start = row_start[n];
        const unsigned end = row_start[n + 1];
        const unsigned cnt = end - start;
        float ax0 = 0.f, ay0 = 0.f, ax1 = 0.f, ay1 = 0.f;
        unsigned i = start;
        for (; i + 4 <= end; i += 4) {
            int sA = src_sorted[i + half];
            int sB = src_sorted[i + 2 + half];
            unsigned pA = y32[sA * 32 + l31];
            unsigned pB = y32[sB * 32 + l31];
            ax0 += __uint_as_float(pA << 16);
            ay0 += __uint_as_float(pA & 0xffff0000u);
            ax1 += __uint_as_float(pB << 16);
            ay1 += __uint_as_float(pB & 0xffff0000u);
        }
        // tail (0..3 edges): low half only
        for (; i < end; ++i) {
            if (half == 0) {
                unsigned p = y32[src_sorted[i] * 32 + l31];
                ax0 += __uint_as_float(p << 16);
                ay0 += __uint_as_float(p & 0xffff0000u);
            }
        }
        float ax = ax0 + ax1, ay = ay0 + ay1;
        ax += __shfl_xor(ax, 32);
        ay += __shfl_xor(ay, 32);
        float w = cnt ? rsqrtf((float)cnt) : 0.f;
        if (half == 0) {
            *(float2*)(h + n * D + l31 * 2) = make_float2(ax * w, ay * w);
        }
    }
}

// out = leaky(h@W1+b1) + leaky((x*h)@W2+b2) via mfma_f32_16x16x32_bf16.
__global__ __launch_bounds__(256) void dense_mfma_kernel(const float* __restrict__ x,
                                                         const float* __restrict__ W1,
                                                         const float* __restrict__ b1,
                                                         const float* __restrict__ W2,
                                                         const float* __restrict__ b2,
                                                         float* hout) {
    const int lane = threadIdx.x & 63;
    const int lo = lane & 15;
    const int hi = lane >> 4;

    bf16x8 bw1[2][4], bw2[2][4];
#pragma unroll
    for (int kt = 0; kt < 2; ++kt)
#pragma unroll
        for (int nt = 0; nt < 4; ++nt) {
            bf16x8 v1, v2;
#pragma unroll
            for (int j = 0; j < 8; ++j) {
                int k = kt * 32 + hi * 8 + j;
                int n = nt * 16 + lo;
                v1[j] = (__bf16)W1[k * D + n];
                v2[j] = (__bf16)W2[k * D + n];
            }
            bw1[kt][nt] = v1;
            bw2[kt][nt] = v2;
        }
    float bb1[4], bb2[4];
#pragma unroll
    for (int nt = 0; nt < 4; ++nt) {
        bb1[nt] = b1[nt * 16 + lo];
        bb2[nt] = b2[nt * 16 + lo];
    }

    int wid = (blockIdx.x * blockDim.x + threadIdx.x) >> 6;
    int nw = (gridDim.x * blockDim.x) >> 6;
    for (int blk = wid; blk < N_NODES / 16; blk += nw) {
        const int rb = blk * 16;
        const float* hrow = hout + (rb + lo) * D;
        const float* xrow = x + (rb + lo) * D;
        bf16x8 ah[2], ag[2];
#pragma unroll
        for (int kt = 0; kt < 2; ++kt) {
            const int c = kt * 32 + hi * 8;
            float4 hv0 = *(const float4*)(hrow + c);
            float4 hv1 = *(const float4*)(hrow + c + 4);
            float4 xv0 = *(const float4*)(xrow + c);
            float4 xv1 = *(const float4*)(xrow + c + 4);
            bf16x8 a, g;
            a[0] = (__bf16)hv0.x; g[0] = (__bf16)(hv0.x * xv0.x);
            a[1] = (__bf16)hv0.y; g[1] = (__bf16)(hv0.y * xv0.y);
            a[2] = (__bf16)hv0.z; g[2] = (__bf16)(hv0.z * xv0.z);
            a[3] = (__bf16)hv0.w; g[3] = (__bf16)(hv0.w * xv0.w);
            a[4] = (__bf16)hv1.x; g[4] = (__bf16)(hv1.x * xv1.x);
            a[5] = (__bf16)hv1.y; g[5] = (__bf16)(hv1.y * xv1.y);
            a[6] = (__bf16)hv1.z; g[6] = (__bf16)(hv1.z * xv1.z);
            a[7] = (__bf16)hv1.w; g[7] = (__bf16)(hv1.w * xv1.w);
            ah[kt] = a;
            ag[kt] = g;
        }
        f32x4 acc1[4], acc2[4];
#pragma unroll
        for (int nt = 0; nt < 4; ++nt) {
            acc1[nt] = (f32x4){0.f, 0.f, 0.f, 0.f};
            acc2[nt] = (f32x4){0.f, 0.f, 0.f, 0.f};
        }
#pragma unroll
        for (int kt = 0; kt < 2; ++kt)
#pragma unroll
            for (int nt = 0; nt < 4; ++nt) {
                acc1[nt] = __builtin_amdgcn_mfma_f32_16x16x32_bf16(ah[kt], bw1[kt][nt], acc1[nt], 0, 0, 0);
                acc2[nt] = __builtin_amdgcn_mfma_f32_16x16x32_bf16(ag[kt], bw2[kt][nt], acc2[nt], 0, 0, 0);
            }
#pragma unroll
        for (int nt = 0; nt < 4; ++nt)
#pragma unroll
            for (int r = 0; r < 4; ++r) {
                float a1 = acc1[nt][r] + bb1[nt];
                float a2 = acc2[nt][r] + bb2[nt];
                a1 = (a1 >= 0.f) ? a1 : 0.2f * a1;
                a2 = (a2 >= 0.f) ? a2 : 0.2f * a2;
                hout[(rb + hi * 4 + r) * D + nt * 16 + lo] = a1 + a2;
            }
    }
}

extern "C" void kernel_launch(void* const* d_in, const int* in_sizes, int n_in,
                              void* d_out, int out_size, void* d_ws, size_t ws_size,
                              hipStream_t stream) {
    const float* x  = (const float*)d_in[0];
    const void*  ei = d_in[1];
    const float* W1 = (const float*)d_in[2];
    const float* b1 = (const float*)d_in[3];
    const float* W2 = (const float*)d_in[4];
    const float* b2 = (const float*)d_in[5];
    float* out = (float*)d_out;

    char* ws = (char*)d_ws;
    const size_t K = (size_t)N_NODES * 4;  // 256 KB
    int*      flag         = (int*)ws;                          // 256 B
    unsigned* deg          = (unsigned*)(ws + 256);             // K
    unsigned* row_start    = (unsigned*)(ws + 256 + K);         // K + 256 (65537)
    unsigned* H            = (unsigned*)(ws + 512 + 2 * K);     // K
    unsigned* P            = (unsigned*)(ws + 512 + 3 * K);     // K
    unsigned* bucket_start = (unsigned*)(ws + 512 + 4 * K);     // 1028 B (pad 2KB)
    int*      src_sorted   = (int*)(ws + 2560 + 4 * K);         // 4 MB
    unsigned* y32          = (unsigned*)(ws + 2560 + 4 * K + (size_t)N_EDGES * 4);  // 8 MB

    // pairs scratch lives in d_out: written by scatterA, consumed by bucketB,
    // then fully overwritten by spmm's h. Deterministic.
    unsigned* pairs = (unsigned*)d_out;

    detect_kernel<<<1, 64, 0, stream>>>((const unsigned*)ei, flag);
    histA_kernel<<<NB, 256, 0, stream>>>(ei, flag, H);
    scanH_kernel<<<1, 256, 0, stream>>>(H, P, bucket_start);
    scatterA_kernel<<<NB, 256, 0, stream>>>(ei, flag, P, bucket_start, pairs);
    bucketB_kernel<<<NB, 256, 0, stream>>>(pairs, bucket_start, deg, row_start, src_sorted);
    y_kernel<<<N_NODES * 32 / 256, 256, 0, stream>>>(x, deg, y32);
    spmm_kernel<<<4096, 256, 0, stream>>>(src_sorted, row_start, y32, out);
    dense_mfma_kernel<<<1024, 256, 0, stream>>>(x, W1, b1, W2, b2, out);
}